// Round 2
// baseline (667.626 us; speedup 1.0000x reference)
//
#include <hip/hip_runtime.h>
#include <hip/hip_bf16.h>

#define IN_DIM 128
#define C_DIM 64

// ---------------------------------------------------------------------------
// K1: xp = x @ W  (N x 128 @ 128 x 64, fp32), plus per-node att dots.
// One wave per row: lane = output channel c. W staged in LDS (32 KB).
// ---------------------------------------------------------------------------
__global__ __launch_bounds__(256) void k_gemm(
    const float* __restrict__ x,
    const float* __restrict__ W,
    const float* __restrict__ att_src,
    const float* __restrict__ att_dst,
    float* __restrict__ xp,
    float* __restrict__ s_src,
    float* __restrict__ s_dst,
    int n)
{
    __shared__ float Wl[IN_DIM][C_DIM];   // 32 KB
    __shared__ float xs[4][IN_DIM];       // 2 KB

    const int t    = threadIdx.x;
    const int lane = t & 63;
    const int wave = t >> 6;

    // stage W (one-time): 8192 floats / 256 threads, coalesced
    for (int i = t; i < IN_DIM * C_DIM; i += 256)
        Wl[i >> 6][i & 63] = W[i];

    const float asrc = att_src[lane];
    const float adst = att_dst[lane];

    for (int base = blockIdx.x * 4; base < n; base += gridDim.x * 4) {
        __syncthreads();
        // stage 4 rows of x (512 floats), coalesced
        for (int i = t; i < 4 * IN_DIM; i += 256) {
            int r = base + (i >> 7);
            xs[i >> 7][i & 127] = (r < n) ? x[(size_t)r * IN_DIM + (i & 127)] : 0.f;
        }
        __syncthreads();

        const int row = base + wave;
        if (row < n) {
            float acc = 0.f;
            #pragma unroll 16
            for (int k = 0; k < IN_DIM; ++k)
                acc += xs[wave][k] * Wl[k][lane];   // xs: broadcast; Wl: 2-way (free)

            xp[(size_t)row * C_DIM + lane] = acc;

            float vs = acc * asrc;
            float vd = acc * adst;
            #pragma unroll
            for (int off = 32; off > 0; off >>= 1) {
                vs += __shfl_xor(vs, off, 64);
                vd += __shfl_xor(vd, off, 64);
            }
            if (lane == 0) { s_src[row] = vs; s_dst[row] = vd; }
        }
    }
}

// ---------------------------------------------------------------------------
// K2: per edge: e = sigmoid(s_src[src] + s_dst[dst]); ex = exp(e);
//     denom[dst] += ex.  (Segment-max elided: e in (0,1) so exp can't
//     overflow and alpha = exp(e)/sum exp(e) is mathematically identical.)
// ---------------------------------------------------------------------------
__global__ __launch_bounds__(256) void k_edge1(
    const int* __restrict__ ei,
    const float* __restrict__ s_src,
    const float* __restrict__ s_dst,
    float* __restrict__ ex,
    float* __restrict__ denom,
    int e)
{
    int i = blockIdx.x * 256 + threadIdx.x;
    if (i >= e) return;
    int s = ei[i];
    int d = ei[e + i];
    float z  = s_src[s] + s_dst[d];
    float sg = 1.f / (1.f + __expf(-z));
    float ee = __expf(sg);
    ex[i] = ee;
    atomicAdd(&denom[d], ee);
}

// ---------------------------------------------------------------------------
// K3: wave-per-edge scatter. lane = channel c.
//     gamma = lam*ex/denom[dst] + (1-lam)*beta;  out_acc[dst][c] += xp[src][c]*gamma
// ---------------------------------------------------------------------------
__global__ __launch_bounds__(256) void k_edge2(
    const int* __restrict__ ei,
    const float* __restrict__ beta,
    const float* __restrict__ lam01,
    const float* __restrict__ ex,
    const float* __restrict__ denom,
    const float* __restrict__ xp,
    float* __restrict__ out_acc,
    int e)
{
    const int lane = threadIdx.x & 63;
    const int widx = blockIdx.x * 4 + (threadIdx.x >> 6);
    if (widx >= e) return;

    const float lam = lam01[0];
    const int s = ei[widx];
    const int d = ei[e + widx];
    const float alpha = ex[widx] / (denom[d] + 1e-16f);
    const float gamma = lam * alpha + (1.f - lam) * beta[widx];

    const float v = xp[(size_t)s * C_DIM + lane] * gamma;
    atomicAdd(&out_acc[(size_t)d * C_DIM + lane], v);
}

// ---------------------------------------------------------------------------
// K4: fp32 accumulator -> fp32 output (mean over H=1 is identity)
// ---------------------------------------------------------------------------
__global__ __launch_bounds__(256) void k_final(
    const float* __restrict__ acc,
    float* __restrict__ out,
    int n)
{
    int i = blockIdx.x * 256 + threadIdx.x;
    if (i < n) out[i] = acc[i];
}

extern "C" void kernel_launch(void* const* d_in, const int* in_sizes, int n_in,
                              void* d_out, int out_size, void* d_ws, size_t ws_size,
                              hipStream_t stream)
{
    const float* x       = (const float*)d_in[0];
    const int*   ei      = (const int*)d_in[1];
    const float* beta    = (const float*)d_in[2];
    const float* lam01   = (const float*)d_in[3];
    const float* W       = (const float*)d_in[4];
    const float* att_src = (const float*)d_in[5];
    const float* att_dst = (const float*)d_in[6];
    float*       out     = (float*)d_out;

    const int n = in_sizes[0] / IN_DIM;   // 100000
    const int e = in_sizes[2];            // 1600000

    // workspace layout (fp32):
    //   out_acc : n*64   (25.6 MB)
    //   xp      : n*64   (25.6 MB)
    //   ex      : e      ( 6.4 MB)
    //   s_src   : n
    //   s_dst   : n
    //   denom   : n
    float* out_acc = (float*)d_ws;
    float* xp      = out_acc + (size_t)n * C_DIM;
    float* ex      = xp + (size_t)n * C_DIM;
    float* s_src   = ex + e;
    float* s_dst   = s_src + n;
    float* denom   = s_dst + n;

    hipMemsetAsync(out_acc, 0, (size_t)n * C_DIM * sizeof(float), stream);
    hipMemsetAsync(denom,   0, (size_t)n * sizeof(float), stream);

    k_gemm <<<(n + 3) / 4,          256, 0, stream>>>(x, W, att_src, att_dst, xp, s_src, s_dst, n);
    k_edge1<<<(e + 255) / 256,      256, 0, stream>>>(ei, s_src, s_dst, ex, denom, e);
    k_edge2<<<(e + 3) / 4,          256, 0, stream>>>(ei, beta, lam01, ex, denom, xp, out_acc, e);
    k_final<<<(n * C_DIM + 255) / 256, 256, 0, stream>>>(out_acc, out, n * C_DIM);
}

// Round 3
// 621.949 us; speedup vs baseline: 1.0734x; 1.0734x over previous
//
#include <hip/hip_runtime.h>
#include <hip/hip_bf16.h>

#define IN_DIM 128
#define C_DIM 64

// ---------------------------------------------------------------------------
// K1: xp = x @ W  (N x 128 @ 128 x 64, fp32), plus per-node att dots.
// One wave per row: lane = output channel c. W staged in LDS (32 KB),
// grid-stride so W staging is amortized over ~12 iterations.
// ---------------------------------------------------------------------------
__global__ __launch_bounds__(256) void k_gemm(
    const float* __restrict__ x,
    const float* __restrict__ W,
    const float* __restrict__ att_src,
    const float* __restrict__ att_dst,
    float* __restrict__ xp,
    float* __restrict__ s_src,
    float* __restrict__ s_dst,
    int n)
{
    __shared__ float Wl[IN_DIM][C_DIM];   // 32 KB
    __shared__ float xs[4][IN_DIM];       // 2 KB

    const int t    = threadIdx.x;
    const int lane = t & 63;
    const int wave = t >> 6;

    // stage W once per block (amortized by grid-stride loop)
    for (int i = t; i < IN_DIM * C_DIM; i += 256)
        Wl[i >> 6][i & 63] = W[i];

    const float asrc = att_src[lane];
    const float adst = att_dst[lane];

    for (int base = blockIdx.x * 4; base < n; base += gridDim.x * 4) {
        __syncthreads();
        // stage 4 rows of x (512 floats) via float4, coalesced
        for (int i = t; i < 4 * IN_DIM / 4; i += 256) {
            int r = base + (i >> 5);           // i*4 / 128
            int c4 = (i & 31) << 2;
            float4 v = make_float4(0.f, 0.f, 0.f, 0.f);
            if (r < n) v = *(const float4*)&x[(size_t)r * IN_DIM + c4];
            *(float4*)&xs[i >> 5][c4] = v;
        }
        __syncthreads();

        const int row = base + wave;
        if (row < n) {
            float acc = 0.f;
            #pragma unroll 16
            for (int k = 0; k < IN_DIM; ++k)
                acc += xs[wave][k] * Wl[k][lane];   // xs: broadcast; Wl: 2-way (free)

            xp[(size_t)row * C_DIM + lane] = acc;

            float vs = acc * asrc;
            float vd = acc * adst;
            #pragma unroll
            for (int off = 32; off > 0; off >>= 1) {
                vs += __shfl_xor(vs, off, 64);
                vd += __shfl_xor(vd, off, 64);
            }
            if (lane == 0) { s_src[row] = vs; s_dst[row] = vd; }
        }
    }
}

// ---------------------------------------------------------------------------
// K2: per edge: e = sigmoid(s_src[src] + s_dst[dst]); ex = exp(e);
//     denom[dst] += ex.  (Segment-max elided: e in (0,1) so exp can't
//     overflow and alpha = exp(e)/sum exp(e) is mathematically identical.)
// ---------------------------------------------------------------------------
__global__ __launch_bounds__(256) void k_edge1(
    const int* __restrict__ ei_src,
    const int* __restrict__ ei_dst,
    const float* __restrict__ s_src,
    const float* __restrict__ s_dst,
    float* __restrict__ ex,
    float* __restrict__ denom,
    int e)
{
    for (int i = blockIdx.x * 256 + threadIdx.x; i < e; i += gridDim.x * 256) {
        int s = ei_src[i];
        int d = ei_dst[i];
        float z  = s_src[s] + s_dst[d];
        float sg = 1.f / (1.f + __expf(-z));
        float ee = __expf(sg);
        ex[i] = ee;
        atomicAdd(&denom[d], ee);
    }
}

// ---------------------------------------------------------------------------
// K3: scatter-accumulate, grid-stride, 64 edges per wave chunk.
//   phase 1: lane i loads scalars of edge (base+i), COALESCED; computes gamma.
//   phase 2: per edge j, v_readlane broadcasts (s,d,gamma); lane = channel:
//            out[d][lane] += xp[s][lane] * gamma  (atomic).
// ---------------------------------------------------------------------------
__global__ __launch_bounds__(256) void k_edge2(
    const int* __restrict__ ei_src,
    const int* __restrict__ ei_dst,
    const float* __restrict__ beta,
    const float* __restrict__ lam01,
    const float* __restrict__ ex,
    const float* __restrict__ denom,
    const float* __restrict__ xp,
    float* __restrict__ out,
    int e)
{
    const int lane = threadIdx.x & 63;
    const int gw   = (blockIdx.x * 256 + threadIdx.x) >> 6;   // global wave id
    const int GW   = (gridDim.x * 256) >> 6;

    const float lam = lam01[0];
    const float oml = 1.f - lam;

    for (int base = gw * 64; base < e; base += GW * 64) {
        const int m = min(64, e - base);

        int s = 0, d = 0; float gamma = 0.f;
        if (lane < m) {
            int idx = base + lane;
            s = ei_src[idx];
            d = ei_dst[idx];
            gamma = lam * ex[idx] / (denom[d] + 1e-16f) + oml * beta[idx];
        }

        for (int j = 0; j < m; ++j) {
            int   sj = __builtin_amdgcn_readlane(s, j);
            int   dj = __builtin_amdgcn_readlane(d, j);
            float gj = __uint_as_float(__builtin_amdgcn_readlane(__float_as_uint(gamma), j));
            float v  = xp[(size_t)sj * C_DIM + lane] * gj;
            atomicAdd(&out[(size_t)dj * C_DIM + lane], v);
        }
    }
}

extern "C" void kernel_launch(void* const* d_in, const int* in_sizes, int n_in,
                              void* d_out, int out_size, void* d_ws, size_t ws_size,
                              hipStream_t stream)
{
    const float* x       = (const float*)d_in[0];
    const int*   ei      = (const int*)d_in[1];
    const float* beta    = (const float*)d_in[2];
    const float* lam01   = (const float*)d_in[3];
    const float* W       = (const float*)d_in[4];
    const float* att_src = (const float*)d_in[5];
    const float* att_dst = (const float*)d_in[6];
    float*       out     = (float*)d_out;

    const int n = in_sizes[0] / IN_DIM;   // 100000
    const int e = in_sizes[2];            // 1600000

    // workspace layout (fp32):
    //   xp      : n*64   (25.6 MB)
    //   ex      : e      ( 6.4 MB)
    //   s_src   : n
    //   s_dst   : n
    //   denom   : n
    float* xp    = (float*)d_ws;
    float* ex    = xp + (size_t)n * C_DIM;
    float* s_src = ex + e;
    float* s_dst = s_src + n;
    float* denom = s_dst + n;

    hipMemsetAsync(out,   0, (size_t)n * C_DIM * sizeof(float), stream);
    hipMemsetAsync(denom, 0, (size_t)n * sizeof(float), stream);

    k_gemm <<<2048, 256, 0, stream>>>(x, W, att_src, att_dst, xp, s_src, s_dst, n);
    k_edge1<<<2048, 256, 0, stream>>>(ei, ei + e, s_src, s_dst, ex, denom, e);
    k_edge2<<<2048, 256, 0, stream>>>(ei, ei + e, beta, lam01, ex, denom, xp, out, e);
}

// Round 4
// 436.364 us; speedup vs baseline: 1.5300x; 1.4253x over previous
//
#include <hip/hip_runtime.h>
#include <hip/hip_bf16.h>

#define IN_DIM 128
#define C_DIM 64

typedef __attribute__((ext_vector_type(8))) short bf16x8;
typedef __attribute__((ext_vector_type(4))) float f32x4;

__device__ __forceinline__ short f2b(float f) {
    unsigned u = __float_as_uint(f);
    unsigned r = (u + 0x7FFFu + ((u >> 16) & 1u)) >> 16;   // RNE to bf16
    return (short)r;
}

// ---------------------------------------------------------------------------
// K1: xp = x @ W via MFMA bf16 (fp32 in, fp32 out, bf16 multiply).
// Wave = one 16-row stripe; 4 n-tiles of 16 cols; K = 128 in 4 steps of 32.
// W staged once per block in LDS, transposed: WT[n][k], row stride 136 bf16
// (16B-aligned rows, bank stride 4 -> 2-way conflict = free).
// A-frags read directly from global: 16 rows x 128B contiguous per wave.
// ---------------------------------------------------------------------------
__global__ __launch_bounds__(256) void k_gemm(
    const float* __restrict__ x,
    const float* __restrict__ W,
    float* __restrict__ xp,
    int n)
{
    __shared__ short WT[C_DIM][136];

    const int t = threadIdx.x;
    for (int i = t; i < IN_DIM * C_DIM; i += 256) {
        int k = i >> 6, nn = i & 63;
        WT[nn][k] = f2b(W[i]);
    }
    __syncthreads();

    const int lane = t & 63;
    const int wv   = t >> 6;
    const int stripe = blockIdx.x * 4 + wv;
    const int base   = stripe * 16;
    if (base >= n) return;

    const int m    = lane & 15;
    const int quad = lane >> 4;
    int rowA = base + m;
    if (rowA >= n) rowA = n - 1;               // clamp (n%16==0 anyway)
    const float* xr = x + (size_t)rowA * IN_DIM + quad * 8;

    f32x4 acc[4] = {{0,0,0,0},{0,0,0,0},{0,0,0,0},{0,0,0,0}};

    #pragma unroll
    for (int ks = 0; ks < 4; ++ks) {
        float4 f0 = *(const float4*)(xr + ks * 32);
        float4 f1 = *(const float4*)(xr + ks * 32 + 4);
        bf16x8 a;
        a[0] = f2b(f0.x); a[1] = f2b(f0.y); a[2] = f2b(f0.z); a[3] = f2b(f0.w);
        a[4] = f2b(f1.x); a[5] = f2b(f1.y); a[6] = f2b(f1.z); a[7] = f2b(f1.w);
        #pragma unroll
        for (int nt = 0; nt < 4; ++nt) {
            bf16x8 b = *(const bf16x8*)&WT[nt * 16 + m][ks * 32 + quad * 8];
            acc[nt] = __builtin_amdgcn_mfma_f32_16x16x32_bf16(a, b, acc[nt], 0, 0, 0);
        }
    }

    // C/D layout: col = lane&15, row = quad*4 + reg   [measured m89]
    #pragma unroll
    for (int nt = 0; nt < 4; ++nt) {
        #pragma unroll
        for (int q = 0; q < 4; ++q) {
            int r = base + quad * 4 + q;
            if (r < n) xp[(size_t)r * C_DIM + nt * 16 + m] = acc[nt][q];
        }
    }
}

// ---------------------------------------------------------------------------
// K2: per-node attention dots. Wave per row, lane = channel.
// ---------------------------------------------------------------------------
__global__ __launch_bounds__(256) void k_att(
    const float* __restrict__ xp,
    const float* __restrict__ att_src,
    const float* __restrict__ att_dst,
    float* __restrict__ s_src,
    float* __restrict__ s_dst,
    int n)
{
    const int lane = threadIdx.x & 63;
    const int gw   = (blockIdx.x * 256 + threadIdx.x) >> 6;
    const int GW   = (gridDim.x * 256) >> 6;
    const float as_ = att_src[lane];
    const float ad_ = att_dst[lane];

    for (int row = gw; row < n; row += GW) {
        float v  = xp[(size_t)row * C_DIM + lane];
        float vs = v * as_;
        float vd = v * ad_;
        #pragma unroll
        for (int off = 32; off > 0; off >>= 1) {
            vs += __shfl_xor(vs, off, 64);
            vd += __shfl_xor(vd, off, 64);
        }
        if (lane == 0) { s_src[row] = vs; s_dst[row] = vd; }
    }
}

// ---------------------------------------------------------------------------
// K3: per-edge ex = exp(sigmoid(...)); denom[dst] += ex; deg[dst]++.
// (Segment-max elided: e in (0,1), exp safe, alpha mathematically identical.)
// ---------------------------------------------------------------------------
__global__ __launch_bounds__(256) void k_edge1(
    const int* __restrict__ ei_src,
    const int* __restrict__ ei_dst,
    const float* __restrict__ s_src,
    const float* __restrict__ s_dst,
    float* __restrict__ ex,
    float* __restrict__ denom,
    int* __restrict__ deg,
    int e)
{
    for (int i = blockIdx.x * 256 + threadIdx.x; i < e; i += gridDim.x * 256) {
        int s = ei_src[i];
        int d = ei_dst[i];
        float z  = s_src[s] + s_dst[d];
        float sg = 1.f / (1.f + __expf(-z));
        float ee = __expf(sg);
        ex[i] = ee;
        atomicAdd(&denom[d], ee);
        atomicAdd(&deg[d], 1);
    }
}

// ---------------------------------------------------------------------------
// Scan (3 kernels): deg -> exclusive offs (+ cursor copy).
// ---------------------------------------------------------------------------
__global__ __launch_bounds__(256) void k_scan1(
    const int* __restrict__ deg, int* __restrict__ bsum, int n)
{
    const int t = threadIdx.x, lane = t & 63, wv = t >> 6;
    int i = blockIdx.x * 256 + t;
    int v = (i < n) ? deg[i] : 0;
    #pragma unroll
    for (int off = 32; off > 0; off >>= 1) v += __shfl_xor(v, off, 64);
    __shared__ int wsum[4];
    if (lane == 0) wsum[wv] = v;
    __syncthreads();
    if (t == 0) bsum[blockIdx.x] = wsum[0] + wsum[1] + wsum[2] + wsum[3];
}

__global__ __launch_bounds__(512) void k_scan2(
    const int* __restrict__ bsum, int* __restrict__ bpre,
    int nb, int* __restrict__ offs, int n, int e)
{
    __shared__ int buf[512];
    const int t = threadIdx.x;
    int v = (t < nb) ? bsum[t] : 0;
    buf[t] = v;
    __syncthreads();
    #pragma unroll
    for (int off = 1; off < 512; off <<= 1) {
        int add = (t >= off) ? buf[t - off] : 0;
        __syncthreads();
        buf[t] += add;
        __syncthreads();
    }
    if (t < nb) bpre[t] = buf[t] - v;   // exclusive
    if (t == 0) offs[n] = e;
}

__global__ __launch_bounds__(256) void k_scan3(
    const int* __restrict__ deg, const int* __restrict__ bpre,
    int* __restrict__ offs, int* __restrict__ cursor, int n)
{
    __shared__ int buf[256];
    const int t = threadIdx.x;
    int i = blockIdx.x * 256 + t;
    int v = (i < n) ? deg[i] : 0;
    buf[t] = v;
    __syncthreads();
    #pragma unroll
    for (int off = 1; off < 256; off <<= 1) {
        int add = (t >= off) ? buf[t - off] : 0;
        __syncthreads();
        buf[t] += add;
        __syncthreads();
    }
    if (i < n) {
        int o = bpre[blockIdx.x] + buf[t] - v;
        offs[i]   = o;
        cursor[i] = o;
    }
}

// ---------------------------------------------------------------------------
// K4: scatter edges into dst-sorted order with final gamma.
// ---------------------------------------------------------------------------
__global__ __launch_bounds__(256) void k_scatter(
    const int* __restrict__ ei_src,
    const int* __restrict__ ei_dst,
    const float* __restrict__ beta,
    const float* __restrict__ lam01,
    const float* __restrict__ ex,
    const float* __restrict__ denom,
    int* __restrict__ cursor,
    int2* __restrict__ srcg,
    int e)
{
    const float lam = lam01[0];
    const float oml = 1.f - lam;
    for (int i = blockIdx.x * 256 + threadIdx.x; i < e; i += gridDim.x * 256) {
        int d = ei_dst[i];
        float g = lam * ex[i] / (denom[d] + 1e-16f) + oml * beta[i];
        int slot = atomicAdd(&cursor[d], 1);
        srcg[slot] = make_int2(ei_src[i], __float_as_int(g));
    }
}

// ---------------------------------------------------------------------------
// K5: segmented reduction, wave per dst node, lane = channel. No atomics;
// out written exactly once, coalesced.
// ---------------------------------------------------------------------------
__global__ __launch_bounds__(256) void k_seg(
    const int* __restrict__ offs,
    const int2* __restrict__ srcg,
    const float* __restrict__ xp,
    float* __restrict__ out,
    int n)
{
    const int lane = threadIdx.x & 63;
    const int d    = (blockIdx.x * 256 + threadIdx.x) >> 6;
    if (d >= n) return;

    const int lo = offs[d];
    const int hi = offs[d + 1];

    float acc = 0.f;
    for (int base = lo; base < hi; base += 64) {
        const int cnt = min(64, hi - base);
        int2 v = (lane < cnt) ? srcg[base + lane] : make_int2(0, 0);
        int j = 0;
        for (; j + 4 <= cnt; j += 4) {
            int   s0 = __builtin_amdgcn_readlane(v.x, j);
            float g0 = __uint_as_float(__builtin_amdgcn_readlane(v.y, j));
            int   s1 = __builtin_amdgcn_readlane(v.x, j + 1);
            float g1 = __uint_as_float(__builtin_amdgcn_readlane(v.y, j + 1));
            int   s2 = __builtin_amdgcn_readlane(v.x, j + 2);
            float g2 = __uint_as_float(__builtin_amdgcn_readlane(v.y, j + 2));
            int   s3 = __builtin_amdgcn_readlane(v.x, j + 3);
            float g3 = __uint_as_float(__builtin_amdgcn_readlane(v.y, j + 3));
            float x0 = xp[(size_t)s0 * C_DIM + lane];
            float x1 = xp[(size_t)s1 * C_DIM + lane];
            float x2 = xp[(size_t)s2 * C_DIM + lane];
            float x3 = xp[(size_t)s3 * C_DIM + lane];
            acc = fmaf(x0, g0, acc);
            acc = fmaf(x1, g1, acc);
            acc = fmaf(x2, g2, acc);
            acc = fmaf(x3, g3, acc);
        }
        for (; j < cnt; ++j) {
            int   sj = __builtin_amdgcn_readlane(v.x, j);
            float gj = __uint_as_float(__builtin_amdgcn_readlane(v.y, j));
            acc = fmaf(xp[(size_t)sj * C_DIM + lane], gj, acc);
        }
    }
    out[(size_t)d * C_DIM + lane] = acc;
}

extern "C" void kernel_launch(void* const* d_in, const int* in_sizes, int n_in,
                              void* d_out, int out_size, void* d_ws, size_t ws_size,
                              hipStream_t stream)
{
    const float* x       = (const float*)d_in[0];
    const int*   ei      = (const int*)d_in[1];
    const float* beta    = (const float*)d_in[2];
    const float* lam01   = (const float*)d_in[3];
    const float* W       = (const float*)d_in[4];
    const float* att_src = (const float*)d_in[5];
    const float* att_dst = (const float*)d_in[6];
    float*       out     = (float*)d_out;

    const int n = in_sizes[0] / IN_DIM;   // 100000
    const int e = in_sizes[2];            // 1600000

    // workspace layout (4B units)
    float* xp     = (float*)d_ws;                 // n*64
    float* ex     = xp + (size_t)n * C_DIM;       // e
    float* s_src  = ex + e;                       // n
    float* s_dst  = s_src + n;                    // n
    float* denom  = s_dst + n;                    // n   \ zeroed together
    int*   deg    = (int*)(denom + n);            // n   /
    int*   offs   = deg + n;                      // n+2 (pad keeps int2 aligned)
    int*   cursor = offs + n + 2;                 // n
    int*   bsum   = cursor + n;                   // 512
    int*   bpre   = bsum + 512;                   // 512
    int2*  srcg   = (int2*)(bpre + 512);          // e int2

    const int nb = (n + 255) / 256;               // 391 <= 512

    hipMemsetAsync(denom, 0, (size_t)2 * n * sizeof(float), stream);

    k_gemm   <<<(n + 63) / 64, 256, 0, stream>>>(x, W, xp, n);
    k_att    <<<1024, 256, 0, stream>>>(xp, att_src, att_dst, s_src, s_dst, n);
    k_edge1  <<<2048, 256, 0, stream>>>(ei, ei + e, s_src, s_dst, ex, denom, deg, e);
    k_scan1  <<<nb, 256, 0, stream>>>(deg, bsum, n);
    k_scan2  <<<1, 512, 0, stream>>>(bsum, bpre, nb, offs, n, e);
    k_scan3  <<<nb, 256, 0, stream>>>(deg, bpre, offs, cursor, n);
    k_scatter<<<2048, 256, 0, stream>>>(ei, ei + e, beta, lam01, ex, denom, cursor, srcg, e);
    k_seg    <<<(n + 3) / 4, 256, 0, stream>>>(offs, srcg, xp, out, n);
}

// Round 5
// 343.677 us; speedup vs baseline: 1.9426x; 1.2697x over previous
//
#include <hip/hip_runtime.h>
#include <hip/hip_bf16.h>
#include <hip/hip_fp16.h>

#define IN_DIM 128
#define C_DIM 64

typedef __attribute__((ext_vector_type(8))) short bf16x8;
typedef __attribute__((ext_vector_type(4))) float f32x4;

__device__ __forceinline__ short f2b(float f) {
    unsigned u = __float_as_uint(f);
    unsigned r = (u + 0x7FFFu + ((u >> 16) & 1u)) >> 16;   // RNE to bf16
    return (short)r;
}
__device__ __forceinline__ float h2f_lo(int p) {
    return __half2float(__ushort_as_half((unsigned short)(p & 0xFFFF)));
}
__device__ __forceinline__ float h2f_hi(int p) {
    return __half2float(__ushort_as_half((unsigned short)((unsigned)p >> 16)));
}

// ---------------------------------------------------------------------------
// K1: xp = x @ W via MFMA bf16, with attention-dot epilogue fused.
// Wave = one 16-row stripe; 4 n-tiles of 16; K=128 in 4 steps of 32.
// W in LDS transposed (row stride 136 bf16 -> 2-way bank alias, free).
// C/D layout: col = lane&15, row = quad*4 + reg  [measured m89]
// ---------------------------------------------------------------------------
__global__ __launch_bounds__(256) void k_gemm(
    const float* __restrict__ x,
    const float* __restrict__ W,
    const float* __restrict__ att_src,
    const float* __restrict__ att_dst,
    float* __restrict__ xp,
    float* __restrict__ s_src,
    float* __restrict__ s_dst,
    int n)
{
    __shared__ short WT[C_DIM][136];

    const int t = threadIdx.x;
    for (int i = t; i < IN_DIM * C_DIM; i += 256) {
        int k = i >> 6, nn = i & 63;
        WT[nn][k] = f2b(W[i]);
    }
    __syncthreads();

    const int lane = t & 63;
    const int wv   = t >> 6;
    const int base = (blockIdx.x * 4 + wv) * 16;
    if (base >= n) return;

    const int m    = lane & 15;
    const int quad = lane >> 4;
    int rowA = base + m;
    if (rowA >= n) rowA = n - 1;
    const float* xr = x + (size_t)rowA * IN_DIM + quad * 8;

    f32x4 acc[4] = {{0,0,0,0},{0,0,0,0},{0,0,0,0},{0,0,0,0}};

    #pragma unroll
    for (int ks = 0; ks < 4; ++ks) {
        float4 f0 = *(const float4*)(xr + ks * 32);
        float4 f1 = *(const float4*)(xr + ks * 32 + 4);
        bf16x8 a;
        a[0] = f2b(f0.x); a[1] = f2b(f0.y); a[2] = f2b(f0.z); a[3] = f2b(f0.w);
        a[4] = f2b(f1.x); a[5] = f2b(f1.y); a[6] = f2b(f1.z); a[7] = f2b(f1.w);
        #pragma unroll
        for (int nt = 0; nt < 4; ++nt) {
            bf16x8 b = *(const bf16x8*)&WT[nt * 16 + m][ks * 32 + quad * 8];
            acc[nt] = __builtin_amdgcn_mfma_f32_16x16x32_bf16(a, b, acc[nt], 0, 0, 0);
        }
    }

    // fused attention dots: row r's channels live in the 16 lanes of this quad
    float asv[4], adv[4];
    #pragma unroll
    for (int nt = 0; nt < 4; ++nt) {
        asv[nt] = att_src[nt * 16 + m];
        adv[nt] = att_dst[nt * 16 + m];
    }
    #pragma unroll
    for (int q = 0; q < 4; ++q) {
        float vs = 0.f, vd = 0.f;
        #pragma unroll
        for (int nt = 0; nt < 4; ++nt) {
            vs = fmaf(acc[nt][q], asv[nt], vs);
            vd = fmaf(acc[nt][q], adv[nt], vd);
        }
        #pragma unroll
        for (int off = 8; off > 0; off >>= 1) {   // reduce across 16 m-lanes
            vs += __shfl_xor(vs, off, 64);
            vd += __shfl_xor(vd, off, 64);
        }
        int r = base + quad * 4 + q;
        if (m == 0 && r < n) { s_src[r] = vs; s_dst[r] = vd; }
    }

    #pragma unroll
    for (int nt = 0; nt < 4; ++nt)
        #pragma unroll
        for (int q = 0; q < 4; ++q) {
            int r = base + quad * 4 + q;
            if (r < n) xp[(size_t)r * C_DIM + nt * 16 + m] = acc[nt][q];
        }
}

// ---------------------------------------------------------------------------
// K2: degree count into per-XCD private copy (atomics stay in one L2).
// MUST use the same grid/block/mapping as k_place so edge->copy matches.
// ---------------------------------------------------------------------------
__global__ __launch_bounds__(256) void k_deg(
    const int* __restrict__ ei_dst,
    int* __restrict__ deg_x,
    int e, int n)
{
    int* my = deg_x + (size_t)(blockIdx.x & 7) * n;
    for (int i = blockIdx.x * 256 + threadIdx.x; i < e; i += gridDim.x * 256)
        atomicAdd(&my[ei_dst[i]], 1);
}

// ---------------------------------------------------------------------------
// Scan over 8n counts in scan order j = d*8 + xcd  (reads deg_x[xcd*n+d]).
// Produces cursor_x[xcd*n+d] (exclusive prefix) and offs_seg[d] (= (d,0)).
// ---------------------------------------------------------------------------
__global__ __launch_bounds__(1024) void k_scan1(
    const int* __restrict__ deg_x, int* __restrict__ bsum, int n)
{
    const int t = threadIdx.x;
    const int j = blockIdx.x * 1024 + t;
    int v = 0;
    if (j < 8 * n) v = deg_x[(size_t)(j & 7) * n + (j >> 3)];
    #pragma unroll
    for (int off = 32; off > 0; off >>= 1) v += __shfl_xor(v, off, 64);
    __shared__ int ws[16];
    if ((t & 63) == 0) ws[t >> 6] = v;
    __syncthreads();
    if (t == 0) {
        int s = 0;
        #pragma unroll
        for (int k = 0; k < 16; ++k) s += ws[k];
        bsum[blockIdx.x] = s;
    }
}

__global__ __launch_bounds__(1024) void k_scan2(
    const int* __restrict__ bsum, int* __restrict__ bpre,
    int nb, int* __restrict__ offs_seg, int n, int e)
{
    __shared__ int buf[1024];
    const int t = threadIdx.x;
    int v = (t < nb) ? bsum[t] : 0;
    buf[t] = v;
    __syncthreads();
    #pragma unroll
    for (int off = 1; off < 1024; off <<= 1) {
        int add = (t >= off) ? buf[t - off] : 0;
        __syncthreads();
        buf[t] += add;
        __syncthreads();
    }
    if (t < nb) bpre[t] = buf[t] - v;   // exclusive
    if (t == 0) offs_seg[n] = e;
}

__global__ __launch_bounds__(1024) void k_scan3(
    const int* __restrict__ deg_x, const int* __restrict__ bpre,
    int* __restrict__ cursor_x, int* __restrict__ offs_seg, int n)
{
    __shared__ int buf[1024];
    const int t = threadIdx.x;
    const int j = blockIdx.x * 1024 + t;
    int v = 0;
    int xcd = j & 7, d = j >> 3;
    if (j < 8 * n) v = deg_x[(size_t)xcd * n + d];
    buf[t] = v;
    __syncthreads();
    #pragma unroll
    for (int off = 1; off < 1024; off <<= 1) {
        int add = (t >= off) ? buf[t - off] : 0;
        __syncthreads();
        buf[t] += add;
        __syncthreads();
    }
    if (j < 8 * n) {
        int g = bpre[blockIdx.x] + buf[t] - v;   // global exclusive prefix
        cursor_x[(size_t)xcd * n + d] = g;
        if (xcd == 0) offs_seg[d] = g;
    }
}

// ---------------------------------------------------------------------------
// K3: place edges into dst-sorted slots. Cursor atomics are XCD-local.
// Stores (src, half2(exp(sigmoid(z)), beta)) -- denom is NOT accumulated
// here; k_seg reduces it per segment (removes all denom atomics).
// ---------------------------------------------------------------------------
__global__ __launch_bounds__(256) void k_place(
    const int* __restrict__ ei_src,
    const int* __restrict__ ei_dst,
    const float* __restrict__ beta,
    const float* __restrict__ s_src,
    const float* __restrict__ s_dst,
    int* __restrict__ cursor_x,
    int2* __restrict__ srcg,
    int e, int n)
{
    int* cur = cursor_x + (size_t)(blockIdx.x & 7) * n;
    for (int i = blockIdx.x * 256 + threadIdx.x; i < e; i += gridDim.x * 256) {
        int s = ei_src[i];
        int d = ei_dst[i];
        float z  = s_src[s] + s_dst[d];
        float sg = 1.f / (1.f + __expf(-z));
        float ee = __expf(sg);
        unsigned pk = (unsigned)__half_as_ushort(__float2half(ee))
                    | ((unsigned)__half_as_ushort(__float2half(beta[i])) << 16);
        int slot = atomicAdd(&cur[d], 1);
        srcg[slot] = make_int2(s, (int)pk);
    }
}

// ---------------------------------------------------------------------------
// K4: segmented reduction, wave per dst, lane = channel. Denominator
// reduced in-wave from the staged half values; out written once, coalesced.
// ---------------------------------------------------------------------------
__global__ __launch_bounds__(256) void k_seg(
    const int* __restrict__ offs_seg,
    const int2* __restrict__ srcg,
    const float* __restrict__ xp,
    const float* __restrict__ lam01,
    float* __restrict__ out,
    int n)
{
    const int lane = threadIdx.x & 63;
    const int d    = (blockIdx.x * 256 + threadIdx.x) >> 6;
    if (d >= n) return;

    const int lo = offs_seg[d];
    const int hi = offs_seg[d + 1];
    const float lam = lam01[0];
    const float oml = 1.f - lam;

    // phase 1: denom = sum of exp(sigmoid) over segment
    float ps = 0.f;
    for (int base = lo; base < hi; base += 64)
        if (base + lane < hi) ps += h2f_lo(srcg[base + lane].y);
    #pragma unroll
    for (int off = 32; off > 0; off >>= 1) ps += __shfl_xor(ps, off, 64);
    const float inv = lam / (ps + 1e-16f);

    // phase 2: accumulate gamma-weighted xp rows
    float acc = 0.f;
    for (int base = lo; base < hi; base += 64) {
        const int cnt = min(64, hi - base);
        int sv = 0; float g = 0.f;
        if (lane < cnt) {
            int2 v = srcg[base + lane];
            sv = v.x;
            g  = inv * h2f_lo(v.y) + oml * h2f_hi(v.y);
        }
        int j = 0;
        for (; j + 4 <= cnt; j += 4) {
            int   s0 = __builtin_amdgcn_readlane(sv, j);
            float g0 = __uint_as_float(__builtin_amdgcn_readlane(__float_as_uint(g), j));
            int   s1 = __builtin_amdgcn_readlane(sv, j + 1);
            float g1 = __uint_as_float(__builtin_amdgcn_readlane(__float_as_uint(g), j + 1));
            int   s2 = __builtin_amdgcn_readlane(sv, j + 2);
            float g2 = __uint_as_float(__builtin_amdgcn_readlane(__float_as_uint(g), j + 2));
            int   s3 = __builtin_amdgcn_readlane(sv, j + 3);
            float g3 = __uint_as_float(__builtin_amdgcn_readlane(__float_as_uint(g), j + 3));
            float x0 = xp[(size_t)s0 * C_DIM + lane];
            float x1 = xp[(size_t)s1 * C_DIM + lane];
            float x2 = xp[(size_t)s2 * C_DIM + lane];
            float x3 = xp[(size_t)s3 * C_DIM + lane];
            acc = fmaf(x0, g0, acc);
            acc = fmaf(x1, g1, acc);
            acc = fmaf(x2, g2, acc);
            acc = fmaf(x3, g3, acc);
        }
        for (; j < cnt; ++j) {
            int   sj = __builtin_amdgcn_readlane(sv, j);
            float gj = __uint_as_float(__builtin_amdgcn_readlane(__float_as_uint(g), j));
            acc = fmaf(xp[(size_t)sj * C_DIM + lane], gj, acc);
        }
    }
    out[(size_t)d * C_DIM + lane] = acc;
}

extern "C" void kernel_launch(void* const* d_in, const int* in_sizes, int n_in,
                              void* d_out, int out_size, void* d_ws, size_t ws_size,
                              hipStream_t stream)
{
    const float* x       = (const float*)d_in[0];
    const int*   ei      = (const int*)d_in[1];
    const float* beta    = (const float*)d_in[2];
    const float* lam01   = (const float*)d_in[3];
    const float* W       = (const float*)d_in[4];
    const float* att_src = (const float*)d_in[5];
    const float* att_dst = (const float*)d_in[6];
    float*       out     = (float*)d_out;

    const int n = in_sizes[0] / IN_DIM;   // 100000
    const int e = in_sizes[2];            // 1600000

    // workspace (4B units); srcg first for int2 alignment
    float* xp       = (float*)d_ws;               // n*64
    int2*  srcg     = (int2*)(xp + (size_t)n * C_DIM);   // e int2 (even offset)
    float* s_src    = (float*)(srcg + e);         // n
    float* s_dst    = s_src + n;                  // n
    int*   deg_x    = (int*)(s_dst + n);          // 8n  (memset 0)
    int*   cursor_x = deg_x + (size_t)8 * n;      // 8n
    int*   offs_seg = cursor_x + (size_t)8 * n;   // n+1
    int*   bsum     = offs_seg + n + 1;           // 1024
    int*   bpre     = bsum + 1024;                // 1024

    const int nb = (8 * n + 1023) / 1024;         // 782 <= 1024

    hipMemsetAsync(deg_x, 0, (size_t)8 * n * sizeof(int), stream);

    k_gemm <<<(n + 63) / 64, 256, 0, stream>>>(x, W, att_src, att_dst, xp, s_src, s_dst, n);
    k_deg  <<<2048, 256, 0, stream>>>(ei + e, deg_x, e, n);
    k_scan1<<<nb, 1024, 0, stream>>>(deg_x, bsum, n);
    k_scan2<<<1, 1024, 0, stream>>>(bsum, bpre, nb, offs_seg, n, e);
    k_scan3<<<nb, 1024, 0, stream>>>(deg_x, bpre, cursor_x, offs_seg, n);
    k_place<<<2048, 256, 0, stream>>>(ei, ei + e, beta, s_src, s_dst, cursor_x, srcg, e, n);
    k_seg  <<<(n + 3) / 4, 256, 0, stream>>>(offs_seg, srcg, xp, lam01, out, n);
}